// Round 1
// baseline (659.987 us; speedup 1.0000x reference)
//
#include <hip/hip_runtime.h>

#define NU 10000
#define NREV_DST 8000
#define MAIN_BLOCKS 512
#define TW (MAIN_BLOCKS * 4)
#define UPW ((NU + TW - 1) / TW)

// ws float layout:
//   [0)      Bstate[8*128]   = 1024
//   [1024)   delta_acc[512]
//   [1536)   Wbuf[8*64]      = 512
//   [2048)   allu[NU*16*64]  = 10,240,000   (slots: call1->0..5, call2->6..10, call3->11..15)

template <int N, int K>
__global__ __launch_bounds__(256) void main_iter(
    const float* __restrict__ emb, const int* __restrict__ idx,
    const float* __restrict__ Sg, const float* __restrict__ Wg,
    float* __restrict__ delta_acc, float* __restrict__ allu,
    int slot0, int write_high, int write_delta)
{
    constexpr int NC = (N + 31) / 32;
    constexpr int P  = NC * 32;

    __shared__ float s_S[64 * 65];
    __shared__ float s_emb[4][32 * 65];
    __shared__ float s_g[4][K * 64];
    __shared__ float s_h[4][K * 64];

    const int tid  = threadIdx.x;
    const int w    = tid >> 6;
    const int lane = tid & 63;
    const int gw   = blockIdx.x * 4 + w;

    // stage S (row-major, stride 65)
    for (int i = tid; i < 64 * 64; i += 256) {
        s_S[(i >> 6) * 65 + (i & 63)] = Sg[i];
    }
    __syncthreads();

    float dreg[NC][K];
#pragma unroll
    for (int c = 0; c < NC; ++c)
#pragma unroll
        for (int k = 0; k < K; ++k) dreg[c][k] = 0.f;

    auto stage = [&](int u, int c, int m) {
        const int npass = (m + 3) >> 2;
        for (int p = 0; p < npass; ++p) {
            const int r = p * 4 + (lane >> 4);
            if (r < m) {
                const int row = idx[u * N + c * 32 + r];
                const float4 v =
                    *reinterpret_cast<const float4*>(emb + (size_t)row * 64 + (lane & 15) * 4);
                float* dst = &s_emb[w][r * 65 + (lane & 15) * 4];
                dst[0] = v.x; dst[1] = v.y; dst[2] = v.z; dst[3] = v.w;
            }
        }
    };

    for (int it = 0; it < UPW; ++it) {
        const int u = gw + it * TW;
        if (u < NU) {
            // ---- phase A: g[k][e=lane] = sum_n W[k][n] * emb[n][e]
            float g[K];
#pragma unroll
            for (int k = 0; k < K; ++k) g[k] = 0.f;
#pragma unroll
            for (int c = 0; c < NC; ++c) {
                const int m = (N - c * 32 < 32) ? (N - c * 32) : 32;
                stage(u, c, m);
                for (int r = 0; r < m; ++r) {
                    const float ev = s_emb[w][r * 65 + lane];
#pragma unroll
                    for (int k = 0; k < K; ++k)
                        g[k] = fmaf(Wg[k * 64 + c * 32 + r], ev, g[k]);  // uniform -> s_load
                }
            }
            // ---- phase B: raw[k][d=lane] = sum_e g[k][e] * S[e][d]
#pragma unroll
            for (int k = 0; k < K; ++k) s_g[w][k * 64 + lane] = g[k];
            float raw[K];
#pragma unroll
            for (int k = 0; k < K; ++k) raw[k] = 0.f;
            for (int e = 0; e < 64; ++e) {
                const float sv = s_S[e * 65 + lane];
#pragma unroll
                for (int k = 0; k < K; ++k) raw[k] = fmaf(s_g[w][k * 64 + e], sv, raw[k]);
            }
            // ---- squash (sum over k, per d)
            float sq = 0.f;
#pragma unroll
            for (int k = 0; k < K; ++k) sq = fmaf(raw[k], raw[k], sq);
            const float f = (sq / (1.0f + sq)) / sqrtf(sq + 1e-9f);
            float hi[K];
#pragma unroll
            for (int k = 0; k < K; ++k) hi[k] = f * raw[k];
            if (write_high) {
#pragma unroll
                for (int k = 0; k < K; ++k)
                    allu[(size_t)u * 1024 + (slot0 + k) * 64 + lane] = hi[k];
            }
            if (write_delta) {
                // ---- phase C: hS[k][e=lane] = sum_d hi[k][d] * S[e][d]
#pragma unroll
                for (int k = 0; k < K; ++k) s_h[w][k * 64 + lane] = hi[k];
                float hs[K];
#pragma unroll
                for (int k = 0; k < K; ++k) hs[k] = 0.f;
                for (int d = 0; d < 64; ++d) {
                    const float sv = s_S[lane * 65 + d];
#pragma unroll
                    for (int k = 0; k < K; ++k) hs[k] = fmaf(s_h[w][k * 64 + d], sv, hs[k]);
                }
#pragma unroll
                for (int k = 0; k < K; ++k) s_g[w][k * 64 + lane] = hs[k];  // reuse as hS buf
                // ---- phase D: delta[k][n] += sum_e emb[n][e] * hS[k][e]
                const int nl = lane & 31, h = lane >> 5;  // lane = (row, e-half)
#pragma unroll
                for (int cc = NC - 1; cc >= 0; --cc) {
                    const int m = (N - cc * 32 < 32) ? (N - cc * 32) : 32;
                    if (cc != NC - 1) stage(u, cc, m);  // last chunk still resident
                    if (nl < m) {
                        for (int eh = 0; eh < 32; ++eh) {
                            const int e = h * 32 + eh;
                            const float ev = s_emb[w][nl * 65 + e];
#pragma unroll
                            for (int k = 0; k < K; ++k)
                                dreg[cc][k] = fmaf(ev, s_g[w][k * 64 + e], dreg[cc][k]);
                        }
                    }
                }
            }
        }
    }

    if (write_delta) {
        __syncthreads();  // all waves done with s_emb (uniform trip counts)
        float* red = &s_emb[w][0];
        const int nl = lane & 31;
#pragma unroll
        for (int cc = 0; cc < NC; ++cc) {
#pragma unroll
            for (int k = 0; k < K; ++k) {
                const float v = dreg[cc][k] + __shfl_xor(dreg[cc][k], 32, 64);
                if (lane < 32) red[k * P + cc * 32 + nl] = v;
            }
        }
        __syncthreads();
        for (int t = tid; t < K * P; t += 256) {
            const float s = s_emb[0][t] + s_emb[1][t] + s_emb[2][t] + s_emb[3][t];
            const int k = t / P, n = t % P;
            atomicAdd(&delta_acc[k * 64 + n], s);
        }
    }
}

// Apply delta -> B, zero delta, compute next softmax W.
__global__ __launch_bounds__(1024) void update_kernel(
    float* __restrict__ Bstate, float* __restrict__ delta_acc,
    const float* __restrict__ Bin, float* __restrict__ Wout,
    int init, int Kc, int nc, int Kn, int nn)
{
    __shared__ float sB[1024];
    const int t = threadIdx.x;
    float b = init ? Bin[t] : Bstate[t];
    const int k = t >> 7, n = t & 127;
    float d = 0.f;
    if (!init && k < Kc && n < nc) d = delta_acc[k * 64 + n];
    __syncthreads();
    if (t < 512) delta_acc[t] = 0.f;  // fresh accumulator for next main launch
    b += d;
    Bstate[t] = b;
    sB[t] = b;
    __syncthreads();
    const int wv = t >> 6, lane = t & 63;
    if (wv < Kn) {
        float v = (lane < nn) ? sB[wv * 128 + lane] : -3.4e38f;
        float m = v;
#pragma unroll
        for (int off = 32; off >= 1; off >>= 1) m = fmaxf(m, __shfl_xor(m, off, 64));
        const float e = (lane < nn) ? expf(v - m) : 0.f;
        float s = e;
#pragma unroll
        for (int off = 32; off >= 1; off >>= 1) s += __shfl_xor(s, off, 64);
        Wout[wv * 64 + lane] = e / s;
    }
}

__global__ __launch_bounds__(256) void attn_kernel(
    const float* __restrict__ allu, const float* __restrict__ M1g,
    const float* __restrict__ M2g, float* __restrict__ out)
{
    __shared__ float sM1[64 * 65];
    __shared__ float sU[4][16 * 64];
    const int tid = threadIdx.x, w = tid >> 6, lane = tid & 63;
    for (int i = tid; i < 4096; i += 256)
        sM1[(i >> 6) * 65 + (i & 63)] = M1g[i];
    __syncthreads();
    const int u = blockIdx.x * 4 + w;
    if (u >= NU) return;
    for (int i = 0; i < 16; ++i)
        sU[w][i * 64 + lane] = allu[(size_t)u * 1024 + i * 64 + lane];
    const float m2 = M2g[lane];
    float acc[16];
#pragma unroll
    for (int i = 0; i < 16; ++i) acc[i] = 0.f;
    for (int d = 0; d < 64; ++d) {
        const float m1v = sM1[d * 65 + lane];
#pragma unroll
        for (int i = 0; i < 16; ++i) acc[i] = fmaf(sU[w][i * 64 + d], m1v, acc[i]);
    }
    float s2[16];
#pragma unroll
    for (int i = 0; i < 16; ++i) {
        float c = tanhf(acc[i]) * m2;
#pragma unroll
        for (int off = 32; off >= 1; off >>= 1) c += __shfl_xor(c, off, 64);
        s2[i] = c * c;
    }
    float mx = 0.f;  // 8 padded slots have s=0
#pragma unroll
    for (int i = 0; i < 16; ++i) mx = fmaxf(mx, s2[i]);
    float den = 8.f * expf(-mx);
    float att[16];
#pragma unroll
    for (int i = 0; i < 16; ++i) { att[i] = expf(s2[i] - mx); den += att[i]; }
    const float inv = 1.0f / den;
    float o = 0.f;
#pragma unroll
    for (int i = 0; i < 16; ++i) o = fmaf(att[i] * inv, sU[w][i * 64 + lane], o);
    out[(size_t)u * 64 + lane] = o;
}

__global__ __launch_bounds__(256) void review_kernel(
    const float* __restrict__ tag, const int* __restrict__ idx, float* __restrict__ out)
{
    const int tid = threadIdx.x, w = tid >> 6, lane = tid & 63;
    const int r = blockIdx.x * 4 + w;
    if (r >= NREV_DST) return;
    float acc = 0.f;
    for (int j = 0; j < 20; ++j) {
        const int t = idx[r * 20 + j];
        acc += tag[(size_t)t * 64 + lane];
    }
    out[(size_t)r * 64 + lane] = acc / 20.0f;
}

extern "C" void kernel_launch(void* const* d_in, const int* in_sizes, int n_in,
                              void* d_out, int out_size, void* d_ws, size_t ws_size,
                              hipStream_t stream)
{
    const float* review_embed = (const float*)d_in[0];
    const float* tag_embed    = (const float*)d_in[1];
    const int*   idx_urt      = (const int*)d_in[2];
    const int*   idx_uqt      = (const int*)d_in[3];
    const int*   idx_uprt     = (const int*)d_in[4];
    const int*   idx_rht      = (const int*)d_in[5];
    const float* B_in         = (const float*)d_in[6];
    const float* S_g          = (const float*)d_in[7];
    const float* M1           = (const float*)d_in[8];
    const float* M2           = (const float*)d_in[9];

    float* ws     = (float*)d_ws;
    float* Bstate = ws;
    float* delta  = ws + 1024;
    float* Wbuf   = ws + 1536;
    float* allu   = ws + 2048;
    float* out    = (float*)d_out;

    const dim3 mg(MAIN_BLOCKS), mb(256);
    const dim3 one(1), ub(1024);

    // init: copy B, zero delta, W for call1 (K=6, n=64)
    hipLaunchKernelGGL(update_kernel, one, ub, 0, stream,
                       Bstate, delta, B_in, Wbuf, 1, 0, 0, 6, 64);

    // call 1: review_embed[idx_urt], n=64, K=6, slots 0..5
    for (int itr = 0; itr < 3; ++itr) {
        hipLaunchKernelGGL((main_iter<64, 6>), mg, mb, 0, stream,
                           review_embed, idx_urt, S_g, Wbuf, delta, allu,
                           0, (itr == 2) ? 1 : 0, 1);
        const int Kn = (itr == 2) ? 5 : 6;
        const int nn = (itr == 2) ? 32 : 64;
        hipLaunchKernelGGL(update_kernel, one, ub, 0, stream,
                           Bstate, delta, B_in, Wbuf, 0, 6, 64, Kn, nn);
    }
    // call 2: tag_embed[idx_uqt], n=32, K=5, slots 6..10
    for (int itr = 0; itr < 3; ++itr) {
        hipLaunchKernelGGL((main_iter<32, 5>), mg, mb, 0, stream,
                           tag_embed, idx_uqt, S_g, Wbuf, delta, allu,
                           6, (itr == 2) ? 1 : 0, 1);
        const int nn = (itr == 2) ? 50 : 32;
        hipLaunchKernelGGL(update_kernel, one, ub, 0, stream,
                           Bstate, delta, B_in, Wbuf, 0, 5, 32, 5, nn);
    }
    // call 3: review_embed[idx_uprt], n=50, K=5, slots 11..15
    for (int itr = 0; itr < 3; ++itr) {
        const int last = (itr == 2);
        hipLaunchKernelGGL((main_iter<50, 5>), mg, mb, 0, stream,
                           review_embed, idx_uprt, S_g, Wbuf, delta, allu,
                           11, last, last ? 0 : 1);
        if (!last)
            hipLaunchKernelGGL(update_kernel, one, ub, 0, stream,
                               Bstate, delta, B_in, Wbuf, 0, 5, 50, 5, 50);
    }

    hipLaunchKernelGGL(attn_kernel, dim3((NU + 3) / 4), mb, 0, stream, allu, M1, M2, out);
    hipLaunchKernelGGL(review_kernel, dim3((NREV_DST + 3) / 4), mb, 0, stream,
                       tag_embed, idx_rht, out + (size_t)NU * 64);
}